// Round 6
// baseline (1313.166 us; speedup 1.0000x reference)
//
#include <hip/hip_runtime.h>
#include <hip/hip_bf16.h>
#include <math.h>

#define KG 4        // dst nodes per block in kron kernel (one per wave)
#define KCHUNK 256  // edges staged in LDS per kron chunk

typedef __attribute__((ext_vector_type(8))) short bfrag;   // 8 bf16 (4 VGPRs)
typedef __attribute__((ext_vector_type(4))) float cfrag;   // 4 fp32 acc

__device__ __forceinline__ ushort f2bf(float f) {
    __hip_bfloat16 h = __float2bfloat16(f);
    return *(ushort*)&h;
}
__device__ __forceinline__ float bf2f(ushort u) {
    __hip_bfloat16 h;
    *(ushort*)&h = u;
    return __bfloat162float(h);
}

// ---------------------------------------------------------------- helpers
__device__ __forceinline__ void blockSum2(float& s1, float& s2, float* red) {
    #pragma unroll
    for (int off = 32; off > 0; off >>= 1) {
        s1 += __shfl_xor(s1, off);
        s2 += __shfl_xor(s2, off);
    }
    int lane = threadIdx.x & 63, wid = threadIdx.x >> 6;
    if (lane == 0) { red[wid] = s1; red[4 + wid] = s2; }
    __syncthreads();
    s1 = red[0] + red[1] + red[2] + red[3];
    s2 = red[4] + red[5] + red[6] + red[7];
}

__device__ __forceinline__ float sigmoidf(float x) { return 1.0f / (1.0f + expf(-x)); }

// ---------------------------------------------------------------- bf16 cast
__global__ __launch_bounds__(256) void cast_bf16_kernel(
    const float* __restrict__ x, ushort* __restrict__ y, int n)
{
    int i = (blockIdx.x * 256 + threadIdx.x) * 4;
    if (i < n) {
        float4 v = *(const float4*)(x + i);
        ushort4 o;
        o.x = f2bf(v.x); o.y = f2bf(v.y); o.z = f2bf(v.z); o.w = f2bf(v.w);
        *(ushort4*)(y + i) = o;
    }
}

// ---------------------------------------------------------------- weight prep (bf16 B^T layouts)
// Also: Wk_t[o][a][24] bf16 (o-major, k padded 20->24 with zeros) for kron stage 1.
__global__ __launch_bounds__(256) void prep_w_kernel(
    const float* __restrict__ Wn, const float* __restrict__ Wih,
    const float* __restrict__ Whh, const float* __restrict__ Wc,
    const float* __restrict__ b_ih, const float* __restrict__ b_hh,
    const float* __restrict__ Wp, const float* __restrict__ bp,
    const float* __restrict__ Wk,
    ushort* __restrict__ BTn, ushort* __restrict__ BTrz,
    ushort* __restrict__ BTin, ushort* __restrict__ BThn,
    ushort* __restrict__ BTc, float* __restrict__ bias_rz,
    ushort* __restrict__ BTp, float* __restrict__ bp_pad,
    ushort* __restrict__ Wk_t)
{
    int id = blockIdx.x * 256 + threadIdx.x;
    if (id < 262144) {
        int n = id >> 9, k = id & 511;
        float v = (k < 256) ? Wih[n * 256 + k] : Whh[n * 256 + k - 256];
        BTrz[id] = f2bf(v);
    } else if (id < 327680) {
        int j = id - 262144; int n = j >> 8, k = j & 255;
        BTin[j] = f2bf(Wih[(512 + n) * 256 + k]);
    } else if (id < 393216) {
        int j = id - 327680; int n = j >> 8, k = j & 255;
        BThn[j] = f2bf(Whh[(512 + n) * 256 + k]);
    } else if (id < 458752) {
        int j = id - 393216; int n = j >> 8, k = j & 255;
        BTn[j] = f2bf(Wn[k * 256 + n]);
    } else if (id < 589824) {
        int j = id - 458752; int n = j >> 9, k = j & 511;
        BTc[j] = f2bf(Wc[k * 256 + n]);
    } else if (id < 590336) {
        int n = id - 589824;
        bias_rz[n] = b_ih[n] + b_hh[n];
    } else if (id < 623104) {
        int j = id - 590336; int n = j >> 8, k = j & 255;
        BTp[j] = f2bf((n < 20) ? Wp[k * 20 + n] : 0.f);
    } else if (id < 623232) {
        int n = id - 623104;
        bp_pad[n] = (n < 20) ? bp[n] : 0.f;
    } else if (id < 746112) {
        int j = id - 623232;               // [0, 256*480)
        int o = j / 480, rem = j - o * 480;
        int a = rem / 24, k = rem - a * 24;
        Wk_t[j] = (k < 20) ? f2bf(Wk[(size_t)(a * 20 + k) * 256 + o]) : (ushort)0;
    }
}

// ---------------------------------------------------------------- generic bf16 MFMA GEMM (128x128, BK=64)
__global__ __launch_bounds__(256) void mfma_gemm_kernel(
    const ushort* __restrict__ A1, const ushort* __restrict__ A2, int ksplit, int lda,
    const ushort* __restrict__ B, const float* __restrict__ bias,
    void* __restrict__ Cout, int store_bf16,
    int M, int N, int K, int ldc)
{
    __shared__ ushort As[128 * 64];
    __shared__ ushort Bs[128 * 64];
    int t = threadIdx.x;
    int m0 = blockIdx.x * 128, n0 = blockIdx.y * 128;
    int w = t >> 6, lane = t & 63;
    int q = lane >> 4, r = lane & 15;
    int wm = (w & 1) * 64, wn = (w >> 1) * 64;

    cfrag acc[4][4] = {};

    int srow_base = t >> 3;
    int skc = t & 7;

    for (int k0 = 0; k0 < K; k0 += 64) {
        const ushort* Ap; int kb;
        if (k0 < ksplit) { Ap = A1; kb = k0; } else { Ap = A2; kb = k0 - ksplit; }
        int4 av[4], bv[4];
        #pragma unroll
        for (int i = 0; i < 4; ++i) {
            int row = i * 32 + srow_base;
            int grow = m0 + row;
            av[i] = make_int4(0, 0, 0, 0);
            if (grow < M) av[i] = *(const int4*)(Ap + (size_t)grow * lda + kb + skc * 8);
            bv[i] = *(const int4*)(B + (size_t)(n0 + row) * K + k0 + skc * 8);
        }
        __syncthreads();
        #pragma unroll
        for (int i = 0; i < 4; ++i) {
            int row = i * 32 + srow_base;
            int off = row * 64 + ((skc ^ (row & 7)) * 8);
            *(int4*)&As[off] = av[i];
            *(int4*)&Bs[off] = bv[i];
        }
        __syncthreads();
        #pragma unroll
        for (int s = 0; s < 2; ++s) {
            bfrag af[4], bfr[4];
            int kc = s * 4 + q;
            #pragma unroll
            for (int mi = 0; mi < 4; ++mi) {
                int arow = wm + mi * 16 + r;
                af[mi] = *(const bfrag*)&As[arow * 64 + ((kc ^ (arow & 7)) * 8)];
            }
            #pragma unroll
            for (int ni = 0; ni < 4; ++ni) {
                int brow = wn + ni * 16 + r;
                bfr[ni] = *(const bfrag*)&Bs[brow * 64 + ((kc ^ (brow & 7)) * 8)];
            }
            #pragma unroll
            for (int mi = 0; mi < 4; ++mi)
                #pragma unroll
                for (int ni = 0; ni < 4; ++ni)
                    acc[mi][ni] = __builtin_amdgcn_mfma_f32_16x16x32_bf16(
                        af[mi], bfr[ni], acc[mi][ni], 0, 0, 0);
        }
    }

    float bvld[4];
    #pragma unroll
    for (int ni = 0; ni < 4; ++ni) bvld[ni] = bias[n0 + wn + ni * 16 + r];
    #pragma unroll
    for (int mi = 0; mi < 4; ++mi) {
        #pragma unroll
        for (int v = 0; v < 4; ++v) {
            int grow = m0 + wm + mi * 16 + q * 4 + v;
            if (grow >= M) continue;
            #pragma unroll
            for (int ni = 0; ni < 4; ++ni) {
                int gcol = n0 + wn + ni * 16 + r;
                if (gcol >= N) continue;
                float val = acc[mi][ni][v] + bvld[ni];
                if (store_bf16) ((ushort*)Cout)[(size_t)grow * ldc + gcol] = f2bf(val);
                else            ((float*)Cout)[(size_t)grow * ldc + gcol] = val;
            }
        }
    }
}

// ---------------------------------------------------------------- LN(20)+relu on npj32 -> npj fp32 + npj_bf [V,24] padded
__global__ __launch_bounds__(256) void ln20_kernel(
    const float* __restrict__ npj32, const float* __restrict__ gp,
    const float* __restrict__ betap, float* __restrict__ npj,
    ushort* __restrict__ npj_bf, int V)
{
    int wid = threadIdx.x >> 6, j = threadIdx.x & 63;
    int v = blockIdx.x * 4 + wid;
    if (v >= V) return;
    float acc = (j < 20) ? npj32[(size_t)v * 32 + j] : 0.f;
    float s1 = acc, s2 = acc * acc;
    #pragma unroll
    for (int off = 32; off > 0; off >>= 1) {
        s1 += __shfl_xor(s1, off);
        s2 += __shfl_xor(s2, off);
    }
    float mu = s1 * (1.0f / 20.0f);
    float var = s2 * (1.0f / 20.0f) - mu * mu;
    if (j < 24) {
        ushort ob = 0;
        if (j < 20) {
            float y = (acc - mu) * rsqrtf(var + 1e-5f) * gp[j] + betap[j];
            float ry = fmaxf(y, 0.f);
            npj[(size_t)v * 20 + j] = ry;
            ob = f2bf(ry);
        }
        npj_bf[(size_t)v * 24 + j] = ob;
    }
}

// ---------------------------------------------------------------- CSR build
__global__ __launch_bounds__(256) void deg_kernel(const int* __restrict__ dst, int* __restrict__ deg, int E) {
    int e = blockIdx.x * 256 + threadIdx.x;
    if (e < E) atomicAdd(&deg[dst[e]], 1);
}

__global__ __launch_bounds__(1024) void scan_kernel(const int* __restrict__ deg, int* __restrict__ row, int V) {
    __shared__ int wsum[16];
    __shared__ int carry_sh;
    int t = threadIdx.x, lane = t & 63, wid = t >> 6;
    if (t == 0) carry_sh = 0;
    __syncthreads();
    for (int base = 0; base < V; base += 1024) {
        int i = base + t;
        int val = (i < V) ? deg[i] : 0;
        #pragma unroll
        for (int s = 1; s < 64; s <<= 1) {
            int n = __shfl_up(val, s);
            if (lane >= s) val += n;
        }
        if (lane == 63) wsum[wid] = val;
        __syncthreads();
        if (wid == 0) {
            int x = (lane < 16) ? wsum[lane] : 0;
            #pragma unroll
            for (int s = 1; s < 16; s <<= 1) {
                int n = __shfl_up(x, s);
                if (lane >= s) x += n;
            }
            if (lane < 16) wsum[lane] = x;
        }
        __syncthreads();
        int wprefix = (wid > 0) ? wsum[wid - 1] : 0;
        int c = carry_sh;
        int incl = c + wprefix + val;
        if (i < V) row[i + 1] = incl;
        __syncthreads();
        if (t == 1023) carry_sh = incl;
    }
    if (t == 0) row[0] = 0;
}

__global__ __launch_bounds__(256) void scatter_kernel(
    const int* __restrict__ dst, const int* __restrict__ row,
    int* __restrict__ cnt, int* __restrict__ eorder, int E)
{
    int e = blockIdx.x * 256 + threadIdx.x;
    if (e < E) {
        int d = dst[e];
        int pos = row[d] + atomicAdd(&cnt[d], 1);
        eorder[pos] = e;
    }
}

// ---------------------------------------------------------------- per-node edge-logit projections
__global__ __launch_bounds__(256) void nodeproj_kernel(
    const float* __restrict__ nf, const float* __restrict__ We,
    float* __restrict__ pd, float* __restrict__ ps, int V)
{
    int wid = threadIdx.x >> 6, lane = threadIdx.x & 63;
    int v = blockIdx.x * 4 + wid;
    if (v >= V) return;
    const float* row = nf + (size_t)v * 256;
    int i = lane * 4;
    float4 x  = *(const float4*)(row + i);
    float4 wd = *(const float4*)(We + i);
    float4 wsv = *(const float4*)(We + 256 + i);
    float sd = x.x * wd.x + x.y * wd.y + x.z * wd.z + x.w * wd.w;
    float ss = x.x * wsv.x + x.y * wsv.y + x.z * wsv.z + x.w * wsv.w;
    #pragma unroll
    for (int off = 32; off > 0; off >>= 1) {
        sd += __shfl_xor(sd, off);
        ss += __shfl_xor(ss, off);
    }
    if (lane == 0) { pd[v] = sd; ps[v] = ss; }
}

// ---------------------------------------------------------------- edge prep (eorder order)
__global__ __launch_bounds__(256) void edgeprep_kernel(
    const int* __restrict__ eorder, const int* __restrict__ src, const int* __restrict__ dst,
    const float* __restrict__ pd, const float* __restrict__ ps, const float* __restrict__ be,
    float* __restrict__ logitOrd, int* __restrict__ srcOrd, int E)
{
    int p = blockIdx.x * 256 + threadIdx.x;
    if (p < E) {
        int e = eorder[p];
        int s = src[e], d = dst[e];
        srcOrd[p] = s;
        logitOrd[p] = fmaxf(pd[d] + ps[s] + be[0], 0.f);
    }
}

// ---------------------------------------------------------------- kron branch (MFMA stage 2)
// Stage 1: T_g in LDS transposed bf16, Tt[g][o][24] (a padded 20->24 zeros), built from
// bf16 o-major Wk_t (vector loads) + fp32 npj.
// Stage 2: wave g owns dst v0+g. Edges in groups of 16: A-frag = npj_bf rows (bf16, LDS),
// B-frag = Tt rows; 16x MFMA 16x16x32 (k=24..31 via zero frags on q==3) -> D[edge][256];
// per-edge LN via in-register tile sums + 4 shfl_xor over the 16 col-lanes; masked
// relu-accumulate into kacc; final shfl_xor(16,32) cross-q reduce, q==0 lanes store.
__global__ __launch_bounds__(256) void kron_kernel(
    const float* __restrict__ npj, const ushort* __restrict__ npj_bf,
    const int* __restrict__ srcOrd, const int* __restrict__ rowPtr,
    const ushort* __restrict__ Wk_t, const float* __restrict__ bk,
    const float* __restrict__ gkv, const float* __restrict__ betak,
    ushort* __restrict__ acat, int V)
{
    __shared__ __align__(16) ushort Tt[KG * 256 * 24];   // 48 KB
    __shared__ __align__(16) ushort sEb[KCHUNK * 24];    // 12 KB
    __shared__ float dsh[KG * 20];
    int t = threadIdx.x;
    int v0 = blockIdx.x * KG;

    if (t < KG * 20) {
        int g = t / 20, k = t % 20;
        int vv = v0 + g;
        dsh[t] = (vv < V) ? npj[(size_t)vv * 20 + k] : 0.f;
    }
    __syncthreads();

    float dreg[KG][20];
    #pragma unroll
    for (int g = 0; g < KG; ++g)
        #pragma unroll
        for (int k = 0; k < 20; ++k) dreg[g][k] = dsh[g * 20 + k];

    // ---- stage 1: thread t owns output channel o=t ----
    {
        const uint* wrow_base = (const uint*)Wk_t + (size_t)t * 240;   // 480 ushorts/row
        for (int a = 0; a < 20; ++a) {
            const uint* wrow = wrow_base + a * 12;
            uint4 u0 = *(const uint4*)(wrow);
            uint4 u1 = *(const uint4*)(wrow + 4);
            uint2 u2 = *(const uint2*)(wrow + 8);
            uint us[10] = {u0.x, u0.y, u0.z, u0.w, u1.x, u1.y, u1.z, u1.w, u2.x, u2.y};
            float wv[20];
            #pragma unroll
            for (int i = 0; i < 10; ++i) {
                wv[2 * i]     = __uint_as_float(us[i] << 16);
                wv[2 * i + 1] = __uint_as_float(us[i] & 0xFFFF0000u);
            }
            #pragma unroll
            for (int g = 0; g < KG; ++g) {
                float s = 0.f;
                #pragma unroll
                for (int k = 0; k < 20; ++k) s += dreg[g][k] * wv[k];
                Tt[g * 6144 + t * 24 + a] = f2bf(s);
            }
        }
        #pragma unroll
        for (int g = 0; g < KG; ++g) {
            *(uint*)&Tt[g * 6144 + t * 24 + 20] = 0;
            *(uint*)&Tt[g * 6144 + t * 24 + 22] = 0;
        }
    }
    // Tt reads happen after the chunk loop's first __syncthreads()

    int wid = t >> 6, lane = t & 63;
    int q = lane >> 4, r = lane & 15;
    int v = v0 + wid;

    float bk_r[16], gk_r[16], bt_r[16];
    #pragma unroll
    for (int tl = 0; tl < 16; ++tl) {
        bk_r[tl] = bk[tl * 16 + r];
        gk_r[tl] = gkv[tl * 16 + r];
        bt_r[tl] = betak[tl * 16 + r];
    }

    int eBase = rowPtr[v0];
    int vEnd = (v0 + KG < V) ? (v0 + KG) : V;
    int eEndB = rowPtr[vEnd];
    int myE0 = (v < V) ? rowPtr[v] : 0;
    int myE1 = (v < V) ? rowPtr[v + 1] : 0;

    float kacc[16];
    #pragma unroll
    for (int tl = 0; tl < 16; ++tl) kacc[tl] = 0.f;

    for (int base = eBase; base < eEndB; base += KCHUNK) {
        int nC = eEndB - base; if (nC > KCHUNK) nC = KCHUNK;
        __syncthreads();   // prev chunk consumed; also orders stage-1 Tt writes
        for (int idx = t; idx < nC * 12; idx += 256) {
            int le = idx / 12, wq = idx - le * 12;
            ((uint*)sEb)[le * 12 + wq] =
                ((const uint*)npj_bf)[(size_t)srcOrd[base + le] * 12 + wq];
        }
        __syncthreads();

        int lo = (myE0 > base) ? myE0 : base;
        int hi = (myE1 < base + nC) ? myE1 : base + nC;
        for (int g0 = lo; g0 < hi; g0 += 16) {
            bfrag Af = {};
            if (q < 3 && g0 + r < hi)
                Af = *(const bfrag*)&sEb[(g0 - base + r) * 24 + q * 8];
            cfrag gacc[16] = {};
            #pragma unroll
            for (int tl = 0; tl < 16; ++tl) {
                bfrag Bf = {};
                if (q < 3)
                    Bf = *(const bfrag*)&Tt[wid * 6144 + (tl * 16 + r) * 24 + q * 8];
                gacc[tl] = __builtin_amdgcn_mfma_f32_16x16x32_bf16(Af, Bf, gacc[tl], 0, 0, 0);
            }
            // per-edge LN: rows = edges (row = q*4+vv), cols spread over 16 tiles x 16 lanes
            float s1v[4] = {0.f, 0.f, 0.f, 0.f};
            float s2v[4] = {0.f, 0.f, 0.f, 0.f};
            #pragma unroll
            for (int tl = 0; tl < 16; ++tl)
                #pragma unroll
                for (int vv = 0; vv < 4; ++vv) {
                    float y = gacc[tl][vv] + bk_r[tl];
                    s1v[vv] += y;
                    s2v[vv] += y * y;
                }
            #pragma unroll
            for (int off = 1; off <= 8; off <<= 1)
                #pragma unroll
                for (int vv = 0; vv < 4; ++vv) {
                    s1v[vv] += __shfl_xor(s1v[vv], off);
                    s2v[vv] += __shfl_xor(s2v[vv], off);
                }
            int nValid = hi - g0;
            #pragma unroll
            for (int vv = 0; vv < 4; ++vv) {
                if (q * 4 + vv < nValid) {
                    float mu = s1v[vv] * (1.0f / 256.0f);
                    float rs = rsqrtf(s2v[vv] * (1.0f / 256.0f) - mu * mu + 1e-5f);
                    #pragma unroll
                    for (int tl = 0; tl < 16; ++tl) {
                        float y = gacc[tl][vv] + bk_r[tl];
                        kacc[tl] += fmaxf((y - mu) * rs * gk_r[tl] + bt_r[tl], 0.f);
                    }
                }
            }
        }
    }

    #pragma unroll
    for (int tl = 0; tl < 16; ++tl) {
        kacc[tl] += __shfl_xor(kacc[tl], 16);
        kacc[tl] += __shfl_xor(kacc[tl], 32);
    }
    if (v < V && q == 0) {
        #pragma unroll
        for (int tl = 0; tl < 16; ++tl)
            acat[(size_t)v * 512 + 256 + tl * 16 + r] = f2bf(kacc[tl]);
    }
}

// ---------------------------------------------------------------- attention stats per dst (linear reads)
__global__ __launch_bounds__(256) void att_kernel(
    const float* __restrict__ logitOrd, const int* __restrict__ rowPtr,
    float* __restrict__ mArr, float* __restrict__ invArr, int V)
{
    int wid = threadIdx.x >> 6, lane = threadIdx.x & 63;
    int v = blockIdx.x * 4 + wid;
    if (v >= V) return;
    int e0 = rowPtr[v], e1 = rowPtr[v + 1];
    float m = -1e30f;
    for (int p = e0 + lane; p < e1; p += 64) m = fmaxf(m, logitOrd[p]);
    #pragma unroll
    for (int off = 32; off > 0; off >>= 1) m = fmaxf(m, __shfl_xor(m, off));
    float d = 0.f;
    for (int p = e0 + lane; p < e1; p += 64) d += expf(logitOrd[p] - m);
    #pragma unroll
    for (int off = 32; off > 0; off >>= 1) d += __shfl_xor(d, off);
    if (lane == 0) {
        mArr[v] = m;
        invArr[v] = (e1 > e0) ? (1.0f / d) : 0.f;
    }
}

// ---------------------------------------------------------------- weighted context (bf16 hv, unroll x4)
__global__ __launch_bounds__(256) void ctx_kernel(
    const ushort* __restrict__ hv_bf, const float* __restrict__ logitOrd,
    const float* __restrict__ mArr, const float* __restrict__ invArr,
    const int* __restrict__ srcOrd, const int* __restrict__ rowPtr,
    ushort* __restrict__ ctx_bf, int V)
{
    int v = blockIdx.x;
    int t = threadIdx.x;
    int e0 = rowPtr[v], e1 = rowPtr[v + 1];
    float m = mArr[v], inv = invArr[v];
    float acc = 0.f;
    int p = e0;
    for (; p + 3 < e1; p += 4) {
        int s0 = srcOrd[p], s1 = srcOrd[p + 1], s2 = srcOrd[p + 2], s3 = srcOrd[p + 3];
        float w0 = expf(logitOrd[p] - m) * inv;
        float w1 = expf(logitOrd[p + 1] - m) * inv;
        float w2 = expf(logitOrd[p + 2] - m) * inv;
        float w3 = expf(logitOrd[p + 3] - m) * inv;
        float h0 = bf2f(hv_bf[(size_t)s0 * 256 + t]);
        float h1 = bf2f(hv_bf[(size_t)s1 * 256 + t]);
        float h2 = bf2f(hv_bf[(size_t)s2 * 256 + t]);
        float h3 = bf2f(hv_bf[(size_t)s3 * 256 + t]);
        acc += w0 * h0 + w1 * h1 + w2 * h2 + w3 * h3;
    }
    for (; p < e1; ++p) {
        float wgt = expf(logitOrd[p] - m) * inv;
        acc += wgt * bf2f(hv_bf[(size_t)srcOrd[p] * 256 + t]);
    }
    ctx_bf[(size_t)v * 256 + t] = f2bf(fmaxf(acc, 0.f));
}

// ---------------------------------------------------------------- GRU gates + LN -> bf16 into acat[:,0:256]
__global__ __launch_bounds__(256) void gru_ln_kernel(
    const ushort* __restrict__ rz, const ushort* __restrict__ inb,
    const ushort* __restrict__ hnb, const float* __restrict__ nf,
    const float* __restrict__ g_ln, const float* __restrict__ b_ln,
    ushort* __restrict__ acat, int V)
{
    __shared__ float red[8];
    int v = blockIdx.x, t = threadIdx.x;
    float r = sigmoidf(bf2f(rz[(size_t)v * 512 + t]));
    float z = sigmoidf(bf2f(rz[(size_t)v * 512 + 256 + t]));
    float n = tanhf(bf2f(inb[(size_t)v * 256 + t]) + r * bf2f(hnb[(size_t)v * 256 + t]));
    float h = (1.f - z) * n + z * nf[(size_t)v * 256 + t];
    float x = fmaxf(h, 0.f);
    float s1 = x, s2 = x * x;
    blockSum2(s1, s2, red);
    float mu = s1 * (1.0f / 256.0f);
    float var = s2 * (1.0f / 256.0f) - mu * mu;
    float y = (x - mu) * rsqrtf(var + 1e-5f) * g_ln[t] + b_ln[t];
    acat[(size_t)v * 512 + t] = f2bf(y);
}

// ---------------------------------------------------------------- row LayerNorm (optional relu)
__global__ __launch_bounds__(256) void ln_kernel(
    const float* __restrict__ in, float* __restrict__ out,
    const float* __restrict__ g, const float* __restrict__ b, int relu_after)
{
    __shared__ float red[8];
    int v = blockIdx.x, t = threadIdx.x;
    float x = in[(size_t)v * 256 + t];
    float s1 = x, s2 = x * x;
    blockSum2(s1, s2, red);
    float mu = s1 * (1.0f / 256.0f);
    float var = s2 * (1.0f / 256.0f) - mu * mu;
    float y = (x - mu) * rsqrtf(var + 1e-5f) * g[t] + b[t];
    if (relu_after) y = fmaxf(y, 0.f);
    out[(size_t)v * 256 + t] = y;
}

// ---------------------------------------------------------------- launcher
extern "C" void kernel_launch(void* const* d_in, const int* in_sizes, int n_in,
                              void* d_out, int out_size, void* d_ws, size_t ws_size,
                              hipStream_t stream)
{
    const float* nf    = (const float*)d_in[0];
    const int*   src   = (const int*)d_in[1];
    const int*   dst   = (const int*)d_in[2];
    const float* Wp    = (const float*)d_in[3];
    const float* bp    = (const float*)d_in[4];
    const float* gp    = (const float*)d_in[5];
    const float* betap = (const float*)d_in[6];
    const float* Wk    = (const float*)d_in[7];
    const float* bk    = (const float*)d_in[8];
    const float* gk    = (const float*)d_in[9];
    const float* betak = (const float*)d_in[10];
    const float* We    = (const float*)d_in[11];
    const float* be    = (const float*)d_in[12];
    const float* Wn    = (const float*)d_in[13];
    const float* bn    = (const float*)d_in[14];
    const float* W_ih  = (const float*)d_in[15];
    const float* W_hh  = (const float*)d_in[16];
    const float* b_ih  = (const float*)d_in[17];
    const float* b_hh  = (const float*)d_in[18];
    const float* g_ln  = (const float*)d_in[19];
    const float* bt_ln = (const float*)d_in[20];
    const float* Wc    = (const float*)d_in[21];
    const float* bc    = (const float*)d_in[22];
    const float* gc    = (const float*)d_in[23];
    const float* betac = (const float*)d_in[24];

    int V = in_sizes[0] / 256;
    int E = in_sizes[1];

    char* w = (char*)d_ws;
    auto alloc = [&](size_t bytes) -> char* {
        char* p = w;
        w += (bytes + 255) & ~(size_t)255;
        return p;
    };
    float*  npj      = (float*)alloc((size_t)V * 20 * 4);
    float*  npj32    = (float*)alloc((size_t)V * 32 * 4);
    ushort* npj_bf   = (ushort*)alloc((size_t)V * 24 * 2);
    ushort* acat     = (ushort*)alloc((size_t)V * 512 * 2);
    ushort* nf_bf    = (ushort*)alloc((size_t)V * 256 * 2);
    ushort* ctx_bf   = (ushort*)alloc((size_t)V * 256 * 2);
    ushort* rz_bf    = (ushort*)alloc((size_t)V * 512 * 2);
    ushort* hv_bf    = rz_bf;  // alias: hv dead before rz GEMM writes
    ushort* in_bf    = (ushort*)alloc((size_t)V * 256 * 2);
    ushort* hn_bf    = (ushort*)alloc((size_t)V * 256 * 2);
    ushort* BTn      = (ushort*)alloc(65536 * 2);
    ushort* BTrz     = (ushort*)alloc(262144 * 2);
    ushort* BTin     = (ushort*)alloc(65536 * 2);
    ushort* BThn     = (ushort*)alloc(65536 * 2);
    ushort* BTc      = (ushort*)alloc(131072 * 2);
    ushort* BTp      = (ushort*)alloc(32768 * 2);
    ushort* Wk_t     = (ushort*)alloc(122880 * 2);
    float*  bias_rz  = (float*)alloc(512 * 4);
    float*  bp_pad   = (float*)alloc(128 * 4);
    float*  logitOrd = (float*)alloc((size_t)E * 4);
    int*    srcOrd   = (int*)alloc((size_t)E * 4);
    float*  pd       = (float*)alloc((size_t)V * 4);
    float*  ps       = (float*)alloc((size_t)V * 4);
    float*  mArr     = (float*)alloc((size_t)V * 4);
    float*  invArr   = (float*)alloc((size_t)V * 4);
    int*    deg      = (int*)alloc((size_t)V * 4);
    int*    cnt      = (int*)alloc((size_t)V * 4);
    int*    rowp     = (int*)alloc((size_t)(V + 1) * 4);
    int*    eorder   = (int*)alloc((size_t)E * 4);

    hipMemsetAsync(deg, 0, (size_t)V * 4, stream);
    hipMemsetAsync(cnt, 0, (size_t)V * 4, stream);

    int mt = (V + 127) / 128;

    cast_bf16_kernel<<<(V * 64 + 255) / 256, 256, 0, stream>>>(nf, nf_bf, V * 256);
    prep_w_kernel<<<(746112 + 255) / 256, 256, 0, stream>>>(
        Wn, W_ih, W_hh, Wc, b_ih, b_hh, Wp, bp, Wk,
        BTn, BTrz, BTin, BThn, BTc, bias_rz, BTp, bp_pad, Wk_t);

    // npj32 = nf @ Wp + bp (N padded to 32)
    mfma_gemm_kernel<<<dim3(mt, 1), 256, 0, stream>>>(
        nf_bf, nf_bf, 256, 256, BTp, bp_pad, npj32, 0, V, 32, 256, 32);
    ln20_kernel<<<(V + 3) / 4, 256, 0, stream>>>(npj32, gp, betap, npj, npj_bf, V);

    deg_kernel<<<(E + 255) / 256, 256, 0, stream>>>(dst, deg, E);
    scan_kernel<<<1, 1024, 0, stream>>>(deg, rowp, V);
    scatter_kernel<<<(E + 255) / 256, 256, 0, stream>>>(dst, rowp, cnt, eorder, E);
    nodeproj_kernel<<<(V + 3) / 4, 256, 0, stream>>>(nf, We, pd, ps, V);
    edgeprep_kernel<<<(E + 255) / 256, 256, 0, stream>>>(
        eorder, src, dst, pd, ps, be, logitOrd, srcOrd, E);

    // hv = nf @ Wn + bn  -> bf16 (aliased on rz_bf; consumed by ctx before rz GEMM)
    mfma_gemm_kernel<<<dim3(mt, 2), 256, 0, stream>>>(
        nf_bf, nf_bf, 256, 256, BTn, bn, hv_bf, 1, V, 256, 256, 256);
    att_kernel<<<(V + 3) / 4, 256, 0, stream>>>(logitOrd, rowp, mArr, invArr, V);
    ctx_kernel<<<V, 256, 0, stream>>>(hv_bf, logitOrd, mArr, invArr, srcOrd, rowp, ctx_bf, V);

    kron_kernel<<<(V + KG - 1) / KG, 256, 0, stream>>>(
        npj, npj_bf, srcOrd, rowp, Wk_t, bk, gk, betak, acat, V);

    // rz = [ctx|nf] @ BTrz + (b_ih+b_hh)
    mfma_gemm_kernel<<<dim3(mt, 4), 256, 0, stream>>>(
        ctx_bf, nf_bf, 256, 256, BTrz, bias_rz, rz_bf, 1, V, 512, 512, 512);
    mfma_gemm_kernel<<<dim3(mt, 2), 256, 0, stream>>>(
        ctx_bf, ctx_bf, 256, 256, BTin, b_ih + 512, in_bf, 1, V, 256, 256, 256);
    mfma_gemm_kernel<<<dim3(mt, 2), 256, 0, stream>>>(
        nf_bf, nf_bf, 256, 256, BThn, b_hh + 512, hn_bf, 1, V, 256, 256, 256);

    gru_ln_kernel<<<V, 256, 0, stream>>>(rz_bf, in_bf, hn_bf, nf, g_ln, bt_ln, acat, V);

    mfma_gemm_kernel<<<dim3(mt, 2), 256, 0, stream>>>(
        acat, acat, 512, 512, BTc, bc, (float*)d_out, 0, V, 256, 512, 256);
    ln_kernel<<<V, 256, 0, stream>>>((float*)d_out, (float*)d_out, gc, betac, 1);
}